// Round 13
// baseline (656.375 us; speedup 1.0000x reference)
//
#include <hip/hip_runtime.h>
#include <math.h>

#define NN   8192
#define DIN  1024
#define DD   256
#define TOPK 30
#define KP   40    // candidate list length per slice (bf16 phase)
#define CAP  88    // per-row per-round append buffer (40+88=128 bitonic)
// SAFETY: doubling schedule only! fixed-threshold filtering admits
// E = m*40/n per round; ratio 2 -> E~40 (CAP=88 is +7sigma), ratio 3 -> E~79 (overflows).
// SAFETY: register budget at launch_bounds(512,4) is ~124 VGPR: single MFMA
// accumulator chain + b[8] + LDS threshold reads ONLY. b[16] (r8) or dual
// accumulators / thrv[16] regs (r9) spill -> 200MB scratch traffic, +60us.
// SAFETY: 2 col-slices is the merge/occupancy sweet spot (r10: 4 slices = +71%
// merge-rounds -> +20us). Per-lane atomic appends beat ballot-aggregation
// (r11: ballot+early-out = +16us; the conflicts overlap MFMA latency for free).
#define NINF -3e38f

typedef short s8v  __attribute__((ext_vector_type(8)));
typedef float f16v __attribute__((ext_vector_type(16)));

// ---------------- wave helpers (wave64) ----------------
__device__ __forceinline__ float wred_sum(float v) {
  v += __shfl_down(v, 32); v += __shfl_down(v, 16); v += __shfl_down(v, 8);
  v += __shfl_down(v, 4);  v += __shfl_down(v, 2);  v += __shfl_down(v, 1);
  return v;  // valid in lane 0
}
__device__ __forceinline__ float wred_max(float v) {
  v = fmaxf(v, __shfl_down(v, 32)); v = fmaxf(v, __shfl_down(v, 16));
  v = fmaxf(v, __shfl_down(v, 8));  v = fmaxf(v, __shfl_down(v, 4));
  v = fmaxf(v, __shfl_down(v, 2));  v = fmaxf(v, __shfl_down(v, 1));
  return v;
}
__device__ __forceinline__ float tanh_fast(float x) {
  return 1.f - 2.f / (__expf(2.f * x) + 1.f);
}
__device__ __forceinline__ unsigned short f2bf(float x) {
  union { float f; unsigned int u; } v; v.f = x;
  unsigned int r = v.u + 0x7FFF + ((v.u >> 16) & 1);
  return (unsigned short)(r >> 16);
}
// strict total order for exact fp32 phase: value desc, index asc
__device__ __forceinline__ bool pair_gt(float v, int i, float pv, int pi) {
  return (v > pv) || (v == pv && i < pi);
}
// monotone float->uint, upper 19 bits of value | 13-bit col (real keys are >0)
__device__ __forceinline__ unsigned key_pack(float f, int col) {
  unsigned b = __float_as_uint(f);
  unsigned u = ((int)b < 0) ? ~b : (b | 0x80000000u);
  return (u & 0xFFFFE000u) | (unsigned)col;
}

// ---------------- generic fp32 GEMM (round-7 proven) ----------------
template<int ACT>
__global__ __launch_bounds__(128, 4)
void gemm_k(const float* __restrict__ A,
            const float* __restrict__ B, const float* __restrict__ bias,
            float* __restrict__ C, int K, int NB)
{
  __shared__ float sA[32 * 36];   // [k][row]
  __shared__ float sB[32 * 68];   // [k][col]
  const int t  = threadIdx.x;
  const int rb = blockIdx.x * 32;
  const int cb = blockIdx.y * 64;
  const int tr = t >> 4;
  const int tc = t & 15;

  float acc[4][4];
#pragma unroll
  for (int u = 0; u < 4; ++u)
#pragma unroll
    for (int j = 0; j < 4; ++j) acc[u][j] = 0.f;

  const int sr  = t >> 2;
  const int sk2 = (t & 3) * 4;

  for (int kt = 0; kt < K; kt += 32) {
    __syncthreads();
    {
      const float* Ap = A + (size_t)(rb + sr) * K + kt;
      float4 va = *(const float4*)(Ap + sk2);
      float4 vb = *(const float4*)(Ap + sk2 + 16);
      sA[(sk2 + 0) * 36 + sr] = va.x; sA[(sk2 + 1) * 36 + sr] = va.y;
      sA[(sk2 + 2) * 36 + sr] = va.z; sA[(sk2 + 3) * 36 + sr] = va.w;
      sA[(sk2 + 16) * 36 + sr] = vb.x; sA[(sk2 + 17) * 36 + sr] = vb.y;
      sA[(sk2 + 18) * 36 + sr] = vb.z; sA[(sk2 + 19) * 36 + sr] = vb.w;
    }
    {
#pragma unroll
      for (int i = 0; i < 4; ++i) {
        const int f4 = t + 128 * i;
        const int k  = f4 >> 4;
        const int c4 = (f4 & 15) << 2;
        *(float4*)&sB[k * 68 + c4] = *(const float4*)&B[(size_t)(kt + k) * NB + cb + c4];
      }
    }
    __syncthreads();
#pragma unroll 8
    for (int k = 0; k < 32; ++k) {
      const float4 bv = *(const float4*)&sB[k * 68 + 4 * tc];
      const float4 av = *(const float4*)&sA[k * 36 + 4 * tr];
      const float a[4] = {av.x, av.y, av.z, av.w};
      const float b[4] = {bv.x, bv.y, bv.z, bv.w};
#pragma unroll
      for (int u = 0; u < 4; ++u)
#pragma unroll
        for (int j = 0; j < 4; ++j) acc[u][j] = fmaf(a[u], b[j], acc[u][j]);
    }
  }

  const float4 bz = *(const float4*)&bias[cb + 4 * tc];
  const float bb[4] = {bz.x, bz.y, bz.z, bz.w};
#pragma unroll
  for (int u = 0; u < 4; ++u) {
    const int row = rb + 4 * tr + u;
    float o[4];
#pragma unroll
    for (int j = 0; j < 4; ++j) {
      o[j] = acc[u][j] + bb[j];
      if (ACT) o[j] = fmaxf(o[j], 0.f);
    }
    float4 ov; ov.x = o[0]; ov.y = o[1]; ov.z = o[2]; ov.w = o[3];
    *(float4*)&C[(size_t)row * NB + cb + 4 * tc] = ov;
  }
}

// ---------------- dual-B GEMM + fused bf16 fragment pack + e_t rowsum ----------------
// C1 = A@B1+b1 (e_h), C2 = A@B2+b2 (e_t). Also writes MFMA-fragment bf16 copies
// and atomically accumulates row sums of C2 into rs (rs must be pre-zeroed).
__global__ __launch_bounds__(128, 4)
void gemm2_k(const float* __restrict__ A,
             const float* __restrict__ B1, const float* __restrict__ bias1,
             float* __restrict__ C1,
             const float* __restrict__ B2, const float* __restrict__ bias2,
             float* __restrict__ C2,
             unsigned short* __restrict__ F1, unsigned short* __restrict__ F2,
             float* __restrict__ rs, int K, int NB)
{
  __shared__ float sA[32 * 36];
  __shared__ float sB1[32 * 68];
  __shared__ float sB2[32 * 68];
  const int t  = threadIdx.x;
  const int rb = blockIdx.x * 32;
  const int cb = blockIdx.y * 64;
  const int tr = t >> 4;
  const int tc = t & 15;

  float acc1[4][4], acc2[4][4];
#pragma unroll
  for (int u = 0; u < 4; ++u)
#pragma unroll
    for (int j = 0; j < 4; ++j) { acc1[u][j] = 0.f; acc2[u][j] = 0.f; }

  const int sr  = t >> 2;
  const int sk2 = (t & 3) * 4;

  for (int kt = 0; kt < K; kt += 32) {
    __syncthreads();
    {
      const float* Ap = A + (size_t)(rb + sr) * K + kt;
      float4 va = *(const float4*)(Ap + sk2);
      float4 vb = *(const float4*)(Ap + sk2 + 16);
      sA[(sk2 + 0) * 36 + sr] = va.x; sA[(sk2 + 1) * 36 + sr] = va.y;
      sA[(sk2 + 2) * 36 + sr] = va.z; sA[(sk2 + 3) * 36 + sr] = va.w;
      sA[(sk2 + 16) * 36 + sr] = vb.x; sA[(sk2 + 17) * 36 + sr] = vb.y;
      sA[(sk2 + 18) * 36 + sr] = vb.z; sA[(sk2 + 19) * 36 + sr] = vb.w;
    }
    {
#pragma unroll
      for (int i = 0; i < 4; ++i) {
        const int f4 = t + 128 * i;
        const int k  = f4 >> 4;
        const int c4 = (f4 & 15) << 2;
        *(float4*)&sB1[k * 68 + c4] = *(const float4*)&B1[(size_t)(kt + k) * NB + cb + c4];
        *(float4*)&sB2[k * 68 + c4] = *(const float4*)&B2[(size_t)(kt + k) * NB + cb + c4];
      }
    }
    __syncthreads();
#pragma unroll 4
    for (int k = 0; k < 32; ++k) {
      const float4 b1 = *(const float4*)&sB1[k * 68 + 4 * tc];
      const float4 b2 = *(const float4*)&sB2[k * 68 + 4 * tc];
      const float4 av = *(const float4*)&sA[k * 36 + 4 * tr];
      const float a[4] = {av.x, av.y, av.z, av.w};
      const float v1[4] = {b1.x, b1.y, b1.z, b1.w};
      const float v2[4] = {b2.x, b2.y, b2.z, b2.w};
#pragma unroll
      for (int u = 0; u < 4; ++u)
#pragma unroll
        for (int j = 0; j < 4; ++j) {
          acc1[u][j] = fmaf(a[u], v1[j], acc1[u][j]);
          acc2[u][j] = fmaf(a[u], v2[j], acc2[u][j]);
        }
    }
  }

  const float4 z1 = *(const float4*)&bias1[cb + 4 * tc];
  const float4 z2 = *(const float4*)&bias2[cb + 4 * tc];
  const float c1b[4] = {z1.x, z1.y, z1.z, z1.w};
  const float c2b[4] = {z2.x, z2.y, z2.z, z2.w};
  // fragment chunk address components (see pack mapping):
  //   T=blockIdx.x, W=4*blockIdx.y+(tc>>2), l=(row&31)|32*((tc>>1)&1), elem off=4*(tc&1)
  const int Wf   = 4 * blockIdx.y + (tc >> 2);
  const int lHi  = ((tc >> 1) & 1) << 5;
  const int eOff = (tc & 1) << 2;
  float rsum[4];
#pragma unroll
  for (int u = 0; u < 4; ++u) {
    const int row = rb + 4 * tr + u;
    float o1[4], o2[4];
#pragma unroll
    for (int j = 0; j < 4; ++j) {
      o1[j] = acc1[u][j] + c1b[j];
      o2[j] = acc2[u][j] + c2b[j];
    }
    rsum[u] = (o2[0] + o2[1]) + (o2[2] + o2[3]);
    float4 w1; w1.x = o1[0]; w1.y = o1[1]; w1.z = o1[2]; w1.w = o1[3];
    float4 w2; w2.x = o2[0]; w2.y = o2[1]; w2.z = o2[2]; w2.w = o2[3];
    *(float4*)&C1[(size_t)row * NB + cb + 4 * tc] = w1;
    *(float4*)&C2[(size_t)row * NB + cb + 4 * tc] = w2;
    // bf16 fragment stores (8 B each)
    const int chunk = (blockIdx.x * 16 + Wf) * 64 + ((row & 31) | lHi);
    uint2 p1, p2;
    p1.x = (unsigned)f2bf(o1[0]) | ((unsigned)f2bf(o1[1]) << 16);
    p1.y = (unsigned)f2bf(o1[2]) | ((unsigned)f2bf(o1[3]) << 16);
    p2.x = (unsigned)f2bf(o2[0]) | ((unsigned)f2bf(o2[1]) << 16);
    p2.y = (unsigned)f2bf(o2[2]) | ((unsigned)f2bf(o2[3]) << 16);
    *(uint2*)&F1[(size_t)chunk * 8 + eOff] = p1;
    *(uint2*)&F2[(size_t)chunk * 8 + eOff] = p2;
  }
  // e_t row-sum partials: reduce over the 16 tc lanes sharing rows
#pragma unroll
  for (int off = 8; off >= 1; off >>= 1)
#pragma unroll
    for (int u = 0; u < 4; ++u)
      rsum[u] += __shfl_down(rsum[u], off);
  if (tc == 0) {
#pragma unroll
    for (int u = 0; u < 4; ++u)
      atomicAdd(&rs[rb + 4 * tr + u], rsum[u]);
  }
}

// ---------------- fused lin1/lin2 GEMM ----------------
__global__ __launch_bounds__(128, 4)
void gemm_lin_k(const float* __restrict__ Eh, const float* __restrict__ En,
                const float* __restrict__ B1, const float* __restrict__ bias1,
                const float* __restrict__ B2, const float* __restrict__ bias2,
                float* __restrict__ C, int K, int NB)
{
  __shared__ float sA1[32 * 36];   // eh+eN
  __shared__ float sA2[32 * 36];   // eh*eN
  __shared__ float sB1[32 * 68];
  __shared__ float sB2[32 * 68];
  const int t  = threadIdx.x;
  const int rb = blockIdx.x * 32;
  const int cb = blockIdx.y * 64;
  const int tr = t >> 4;
  const int tc = t & 15;

  float acc1[4][4], acc2[4][4];
#pragma unroll
  for (int u = 0; u < 4; ++u)
#pragma unroll
    for (int j = 0; j < 4; ++j) { acc1[u][j] = 0.f; acc2[u][j] = 0.f; }

  const int sr  = t >> 2;
  const int sk2 = (t & 3) * 4;

  for (int kt = 0; kt < K; kt += 32) {
    __syncthreads();
    {
      const float* Hp = Eh + (size_t)(rb + sr) * K + kt;
      const float* Np = En + (size_t)(rb + sr) * K + kt;
      const float4 ha = *(const float4*)(Hp + sk2);
      const float4 hb = *(const float4*)(Hp + sk2 + 16);
      const float4 na = *(const float4*)(Np + sk2);
      const float4 nb = *(const float4*)(Np + sk2 + 16);
      sA1[(sk2 + 0) * 36 + sr] = ha.x + na.x; sA2[(sk2 + 0) * 36 + sr] = ha.x * na.x;
      sA1[(sk2 + 1) * 36 + sr] = ha.y + na.y; sA2[(sk2 + 1) * 36 + sr] = ha.y * na.y;
      sA1[(sk2 + 2) * 36 + sr] = ha.z + na.z; sA2[(sk2 + 2) * 36 + sr] = ha.z * na.z;
      sA1[(sk2 + 3) * 36 + sr] = ha.w + na.w; sA2[(sk2 + 3) * 36 + sr] = ha.w * na.w;
      sA1[(sk2 + 16) * 36 + sr] = hb.x + nb.x; sA2[(sk2 + 16) * 36 + sr] = hb.x * nb.x;
      sA1[(sk2 + 17) * 36 + sr] = hb.y + nb.y; sA2[(sk2 + 17) * 36 + sr] = hb.y * nb.y;
      sA1[(sk2 + 18) * 36 + sr] = hb.z + nb.z; sA2[(sk2 + 18) * 36 + sr] = hb.z * nb.z;
      sA1[(sk2 + 19) * 36 + sr] = hb.w + nb.w; sA2[(sk2 + 19) * 36 + sr] = hb.w * nb.w;
    }
    {
#pragma unroll
      for (int i = 0; i < 4; ++i) {
        const int f4 = t + 128 * i;
        const int k  = f4 >> 4;
        const int c4 = (f4 & 15) << 2;
        *(float4*)&sB1[k * 68 + c4] = *(const float4*)&B1[(size_t)(kt + k) * NB + cb + c4];
        *(float4*)&sB2[k * 68 + c4] = *(const float4*)&B2[(size_t)(kt + k) * NB + cb + c4];
      }
    }
    __syncthreads();
#pragma unroll 4
    for (int k = 0; k < 32; ++k) {
      const float4 b1 = *(const float4*)&sB1[k * 68 + 4 * tc];
      const float4 b2 = *(const float4*)&sB2[k * 68 + 4 * tc];
      const float4 a1 = *(const float4*)&sA1[k * 36 + 4 * tr];
      const float4 a2 = *(const float4*)&sA2[k * 36 + 4 * tr];
      const float x1[4] = {a1.x, a1.y, a1.z, a1.w};
      const float x2[4] = {a2.x, a2.y, a2.z, a2.w};
      const float v1[4] = {b1.x, b1.y, b1.z, b1.w};
      const float v2[4] = {b2.x, b2.y, b2.z, b2.w};
#pragma unroll
      for (int u = 0; u < 4; ++u)
#pragma unroll
        for (int j = 0; j < 4; ++j) {
          acc1[u][j] = fmaf(x1[u], v1[j], acc1[u][j]);
          acc2[u][j] = fmaf(x2[u], v2[j], acc2[u][j]);
        }
    }
  }

  const float4 z1 = *(const float4*)&bias1[cb + 4 * tc];
  const float4 z2 = *(const float4*)&bias2[cb + 4 * tc];
  const float c1b[4] = {z1.x, z1.y, z1.z, z1.w};
  const float c2b[4] = {z2.x, z2.y, z2.z, z2.w};
#pragma unroll
  for (int u = 0; u < 4; ++u) {
    const int row = rb + 4 * tr + u;
    float4 ov;
    ov.x = fmaxf(acc1[u][0] + c1b[0], 0.f) + fmaxf(acc2[u][0] + c2b[0], 0.f);
    ov.y = fmaxf(acc1[u][1] + c1b[1], 0.f) + fmaxf(acc2[u][1] + c2b[1], 0.f);
    ov.z = fmaxf(acc1[u][2] + c1b[2], 0.f) + fmaxf(acc2[u][2] + c2b[2], 0.f);
    ov.w = fmaxf(acc1[u][3] + c1b[3], 0.f) + fmaxf(acc2[u][3] + c2b[3], 0.f);
    *(float4*)&C[(size_t)row * NB + cb + 4 * tc] = ov;
  }
}

// ---------------- candidate generation: bf16 MFMA + key-packed top-40 ----------------
// grid (256 row-groups, 2 col-slices) = 512 blocks, 512 threads (8 waves).
// 7 DOUBLING rounds; r7-proven register shape; per-lane atomic appends;
// per-row bitonic-128 merges, 2 rows interleaved per wave.
__global__ __launch_bounds__(512, 4)
void score_cand_k(const unsigned short* __restrict__ ehF,
                  const unsigned short* __restrict__ etF,
                  unsigned* __restrict__ gCand)
{
  __shared__ unsigned sBuf[32 * CAP];
  __shared__ unsigned sK[32][KP];
  __shared__ unsigned sThrK[32];
  __shared__ int      sCnt[32];

  const int t = threadIdx.x, lane = t & 63, w = t >> 6;
  const int g  = blockIdx.x;            // row group
  const int sy = blockIdx.y;            // col slice (0..1)
  const int tile0 = sy * 128;
  const s8v* eh8 = (const s8v*)ehF;
  const s8v* et8 = (const s8v*)etF;

  s8v af[16];
#pragma unroll
  for (int W = 0; W < 16; ++W)
    af[W] = eh8[((size_t)g * 16 + W) * 64 + lane];

  for (int idx = t; idx < 32 * KP; idx += 512) ((unsigned*)sK)[idx] = 0u;
  if (t < 32) { sThrK[t] = 0u; sCnt[t] = 0; }
  __syncthreads();

  const int rq = 4 * (lane >> 5);
  const int colLane = lane & 31;

  int tb = 0;
  for (int rnd = 0; rnd < 7; ++rnd) {
    const int ntile = (rnd == 0) ? 2 : (2 << (rnd - 1));   // 2,2,4,8,16,32,64
    for (int p = w; p < ntile; p += 8) {
      const int T = tile0 + tb + p;
      const s8v* bp = et8 + (size_t)T * 1024 + lane;
      f16v c;
#pragma unroll
      for (int i = 0; i < 16; ++i) c[i] = 0.f;
      {
        s8v b[8];
#pragma unroll
        for (int q = 0; q < 8; ++q) b[q] = bp[q * 64];
#pragma unroll
        for (int q = 0; q < 8; ++q)
          c = __builtin_amdgcn_mfma_f32_32x32x16_bf16(af[q], b[q], c, 0, 0, 0);
#pragma unroll
        for (int q = 0; q < 8; ++q) b[q] = bp[(8 + q) * 64];
#pragma unroll
        for (int q = 0; q < 8; ++q)
          c = __builtin_amdgcn_mfma_f32_32x32x16_bf16(af[8 + q], b[q], c, 0, 0, 0);
      }
      const int col = T * 32 + colLane;
#pragma unroll
      for (int r = 0; r < 16; ++r) {
        const int row = (r & 3) + 8 * (r >> 2) + rq;
        const unsigned key = key_pack(c[r], col);
        if (key > sThrK[row]) {
          const int ix = atomicAdd(&sCnt[row], 1);
          if (ix < CAP) sBuf[row * CAP + ix] = key;
        }
      }
    }
    __syncthreads();

#pragma unroll 1
    for (int rp = 0; rp < 2; ++rp) {
      const int ra = 4 * w + 2 * rp;
      const int rc = ra + 1;
      const int cA = min(sCnt[ra], CAP);
      const int cB = min(sCnt[rc], CAP);
      unsigned a0 = (lane < KP) ? sK[ra][lane]
                                : ((lane - KP) < cA ? sBuf[ra * CAP + (lane - KP)] : 0u);
      unsigned a1 = ((24 + lane) < cA) ? sBuf[ra * CAP + 24 + lane] : 0u;
      unsigned b0 = (lane < KP) ? sK[rc][lane]
                                : ((lane - KP) < cB ? sBuf[rc * CAP + (lane - KP)] : 0u);
      unsigned b1 = ((24 + lane) < cB) ? sBuf[rc * CAP + 24 + lane] : 0u;
#pragma unroll
      for (int k = 2; k <= 128; k <<= 1) {
#pragma unroll
        for (int j = k >> 1; j >= 1; j >>= 1) {
          if (j == 64) {
            unsigned mx = max(a0, a1), mn = min(a0, a1); a0 = mx; a1 = mn;
            mx = max(b0, b1); mn = min(b0, b1); b0 = mx; b1 = mn;
          } else {
            const unsigned pa0 = (unsigned)__shfl_xor((int)a0, j);
            const unsigned pa1 = (unsigned)__shfl_xor((int)a1, j);
            const unsigned pb0 = (unsigned)__shfl_xor((int)b0, j);
            const unsigned pb1 = (unsigned)__shfl_xor((int)b1, j);
            const bool km0 = (((lane & k) == 0)        == ((lane & j) == 0));
            const bool km1 = ((((64 + lane) & k) == 0) == ((lane & j) == 0));
            a0 = km0 ? max(a0, pa0) : min(a0, pa0);
            a1 = km1 ? max(a1, pa1) : min(a1, pa1);
            b0 = km0 ? max(b0, pb0) : min(b0, pb0);
            b1 = km1 ? max(b1, pb1) : min(b1, pb1);
          }
        }
      }
      if (rnd < 6) {
        if (lane < KP) { sK[ra][lane] = a0; sK[rc][lane] = b0; }
        if (lane == KP - 1) { sThrK[ra] = a0; sThrK[rc] = b0; }
        if (lane == 0) { sCnt[ra] = 0; sCnt[rc] = 0; }
      } else {
        if (lane < KP) {
          gCand[(((size_t)g * 2 + sy) * 32 + ra) * KP + lane] = a0;
          gCand[(((size_t)g * 2 + sy) * 32 + rc) * KP + lane] = b0;
        }
      }
    }
    __syncthreads();
    tb += ntile;
  }
}

// ---------------- merge slices + fp32 rescore + exact top-30 ----------------
__global__ __launch_bounds__(512, 2)
void cand_merge_k(const unsigned* __restrict__ gCand,
                  const float* __restrict__ e_h, const float* __restrict__ e_t,
                  float* __restrict__ topv_g, int* __restrict__ topi_g)
{
  __shared__ float    sEh[16 * 256];
  __shared__ unsigned sK40[16][KP];
  __shared__ float    sRes[16][KP];
  const int t = threadIdx.x, lane = t & 63, w = t >> 6;
  const int g = blockIdx.x, rb = g * 32;
  const int r0 = blockIdx.y * 16;

  for (int i = t; i < 1024; i += 512)
    ((float4*)sEh)[i] = ((const float4*)(e_h + (size_t)(rb + r0) * 256))[i];

#pragma unroll 1
  for (int rp = 0; rp < 2; ++rp) {
    const int lr = 2 * w + rp;
    const int r  = r0 + lr;
    unsigned v0, v1;
    {
      const int m = lane;
      const int s = m / 40, q = m - s * 40;
      v0 = gCand[(((size_t)g * 2 + s) * 32 + r) * KP + q];
    }
    {
      const int m = 64 + lane;
      if (m < 80) {
        const int q = m - 40;
        v1 = gCand[(((size_t)g * 2 + 1) * 32 + r) * KP + q];
      } else v1 = 0u;
    }
#pragma unroll
    for (int k = 2; k <= 128; k <<= 1) {
#pragma unroll
      for (int j = k >> 1; j >= 1; j >>= 1) {
        if (j == 64) {
          const unsigned mx = max(v0, v1), mn = min(v0, v1);
          v0 = mx; v1 = mn;
        } else {
          const unsigned p0 = (unsigned)__shfl_xor((int)v0, j);
          const unsigned p1 = (unsigned)__shfl_xor((int)v1, j);
          const bool km0 = (((lane & k) == 0)        == ((lane & j) == 0));
          const bool km1 = ((((64 + lane) & k) == 0) == ((lane & j) == 0));
          v0 = km0 ? max(v0, p0) : min(v0, p0);
          v1 = km1 ? max(v1, p1) : min(v1, p1);
        }
      }
    }
    if (lane < KP) sK40[lr][lane] = v0;
  }
  __syncthreads();

  for (int i = t; i < 16 * KP; i += 512) {
    const int lr = i / KP, q = i - lr * KP;
    const int c = (int)(sK40[lr][q] & 0x1FFFu);
    const float* et = &e_t[(size_t)c * 256];
    const float* eh = &sEh[lr * 256];
    float acc = 0.f;
#pragma unroll 8
    for (int d = 0; d < 64; ++d) {
      const float4 a = *(const float4*)&eh[d * 4];
      const float4 b = *(const float4*)&et[d * 4];
      acc = fmaf(a.x, b.x, acc); acc = fmaf(a.y, b.y, acc);
      acc = fmaf(a.z, b.z, acc); acc = fmaf(a.w, b.w, acc);
    }
    sRes[lr][q] = acc * 0.0625f;                 // SCALE = D^-0.5
  }
  __syncthreads();

#pragma unroll 1
  for (int rp = 0; rp < 2; ++rp) {
    const int lr = 2 * w + rp;
    float v; int c;
    if (lane < KP) { v = sRes[lr][lane]; c = (int)(sK40[lr][lane] & 0x1FFFu); }
    else           { v = NINF;           c = 0x40000000 + lane; }
#pragma unroll
    for (int k = 2; k <= 64; k <<= 1) {
#pragma unroll
      for (int j = k >> 1; j >= 1; j >>= 1) {
        const float pv = __shfl_xor(v, j);
        const int   pc = __shfl_xor(c, j);
        const bool km = (((lane & k) == 0) == ((lane & j) == 0));
        const bool gt = pair_gt(v, c, pv, pc);
        const bool keep = (km == gt);
        v = keep ? v : pv; c = keep ? c : pc;
      }
    }
    if (lane < TOPK) {
      topv_g[(size_t)(rb + r0 + lr) * TOPK + lane] = v;
      topi_g[(size_t)(rb + r0 + lr) * TOPK + lane] = c;
    }
  }
}

// ---------------- gated message construction -> e_Nh ----------------
// Wave-redundant softmaxes (shfl broadcasts, no LDS for sP/sI/sW); one barrier
// for the cross-wave gate reduction. Batched 30-way-ILP shuffle reduction.
__global__ __launch_bounds__(256)
void message_k(const float* __restrict__ e_h, const float* __restrict__ e_t,
               const float* __restrict__ rs, const float* __restrict__ tv_g,
               const int* __restrict__ ti_g, float* __restrict__ e_Nh)
{
  __shared__ float wpart[TOPK][4];
  const int n = blockIdx.x;
  const int t = threadIdx.x, lane = t & 63, w = t >> 6;

  // every wave computes the topk softmax redundantly
  const float v = (lane < TOPK) ? tv_g[(size_t)n * TOPK + lane] : NINF;
  const int  ji = (lane < TOPK) ? ti_g[(size_t)n * TOPK + lane] : 0;
  float m = wred_max(v); m = __shfl(m, 0);
  float pe = (lane < TOPK) ? __expf(v - m) : 0.f;
  float s = wred_sum(pe); s = __shfl(s, 0);
  const float pk = pe / s;                  // lane k holds prob_k

  const float eh = e_h[(size_t)n * DD + t];
  float nbv[TOPK];
  float gg[TOPK];
#pragma unroll
  for (int k = 0; k < TOPK; ++k) {
    const int   j = __shfl(ji, k);
    const float p = __shfl(pk, k);
    const float nb = e_t[(size_t)j * DD + t];
    nbv[k] = nb;
    gg[k] = tanh_fast((2.f - p) * eh + p * nb);
  }
#pragma unroll
  for (int off = 32; off >= 1; off >>= 1)
#pragma unroll
    for (int k = 0; k < TOPK; ++k)
      gg[k] += __shfl_down(gg[k], off);
  if (lane == 0)
#pragma unroll
    for (int k = 0; k < TOPK; ++k) wpart[k][w] = gg[k];
  __syncthreads();

  // every wave computes the ka softmax redundantly
  float kw = NINF;
  if (lane < TOPK) {
    const float gs = wpart[lane][0] + wpart[lane][1] + wpart[lane][2] + wpart[lane][3];
    kw = rs[ji] * gs;
  }
  float m2 = wred_max(kw); m2 = __shfl(m2, 0);
  float p2 = (lane < TOPK) ? __expf(kw - m2) : 0.f;
  float s2 = wred_sum(p2); s2 = __shfl(s2, 0);
  const float wk = p2 / s2;                 // lane k holds ka_prob_k

  float o = 0.f;
#pragma unroll
  for (int k = 0; k < TOPK; ++k) o = fmaf(__shfl(wk, k), nbv[k], o);
  e_Nh[(size_t)n * DD + t] = o;
}

// ---------------- attention readout: att[n] ----------------
__global__ __launch_bounds__(256)
void att_k(const float* __restrict__ e, const float* __restrict__ W1,
           const float* __restrict__ b1, const float* __restrict__ W2,
           const float* __restrict__ b2, float* __restrict__ att)
{
  const int t = threadIdx.x;
  const int q = t >> 7;
  const int m = t & 127;
  const int lane = t & 63, w = t >> 6;
  const int n0 = blockIdx.x * 8 + q * 4;
  float acc[4] = {0.f, 0.f, 0.f, 0.f};
  for (int d = 0; d < DD; ++d) {
    const float wv = W1[d * 128 + m];
#pragma unroll
    for (int rr = 0; rr < 4; ++rr)
      acc[rr] = fmaf(e[(size_t)(n0 + rr) * DD + d], wv, acc[rr]);
  }
  const float b1m = b1[m], w2m = W2[m];
  __shared__ float part[4][4];
#pragma unroll
  for (int rr = 0; rr < 4; ++rr) {
    float v = acc[rr] + b1m;
    v = (v > 0.f) ? v : 0.01f * v;
    v *= w2m;
    v = wred_sum(v);
    if (lane == 0) part[w][rr] = v;
  }
  __syncthreads();
  if (t < 8) {
    const int qq = t >> 2, rr = t & 3;
    att[blockIdx.x * 8 + qq * 4 + rr] = part[qq * 2][rr] + part[qq * 2 + 1][rr] + b2[0];
  }
}

// ---------------- softmax stats over N, zero e_g ----------------
__global__ __launch_bounds__(1024)
void smax_prep_k(const float* __restrict__ att, float* __restrict__ stats,
                 float* __restrict__ eg)
{
  __shared__ float red[16];
  __shared__ float mg;
  const int t = threadIdx.x, lane = t & 63, w = t >> 6;
  float m = NINF;
#pragma unroll
  for (int i = 0; i < 8; ++i) m = fmaxf(m, att[t + 1024 * i]);
  m = wred_max(m);
  if (lane == 0) red[w] = m;
  __syncthreads();
  if (t == 0) {
    float mm = red[0];
    for (int i = 1; i < 16; ++i) mm = fmaxf(mm, red[i]);
    mg = mm;
  }
  __syncthreads();
  const float mm = mg;
  float s = 0.f;
#pragma unroll
  for (int i = 0; i < 8; ++i) s += __expf(att[t + 1024 * i] - mm);
  s = wred_sum(s);
  __syncthreads();
  if (lane == 0) red[w] = s;
  __syncthreads();
  if (t == 0) {
    float ss = 0.f;
    for (int i = 0; i < 16; ++i) ss += red[i];
    stats[0] = mm; stats[1] = ss;
  }
  if (t < DD) eg[t] = 0.f;
}

// ---------------- e_g = sum_n softmax(att)_n * e_n ----------------
// 256 blocks x 32 rows (was 64 x 128: 4x occupancy).
__global__ __launch_bounds__(256)
void eg_k(const float* __restrict__ att, const float* __restrict__ stats,
          const float* __restrict__ e, float* __restrict__ eg)
{
  const int t = threadIdx.x;
  const float m = stats[0], inv = 1.f / stats[1];
  float acc = 0.f;
  const int n0 = blockIdx.x * 32;
  for (int r = 0; r < 32; ++r) {
    const int n = n0 + r;
    acc = fmaf(__expf(att[n] - m), e[(size_t)n * DD + t], acc);
  }
  atomicAdd(&eg[t], acc * inv);
}

// ---------------- launch ----------------
extern "C" void kernel_launch(void* const* d_in, const int* in_sizes, int n_in,
                              void* d_out, int out_size, void* d_ws, size_t ws_size,
                              hipStream_t stream)
{
  const float* x      = (const float*)d_in[0];
  const float* W_fc1  = (const float*)d_in[1];
  const float* b_fc1  = (const float*)d_in[2];
  const float* W_fc2  = (const float*)d_in[3];
  const float* b_fc2  = (const float*)d_in[4];
  const float* W_head = (const float*)d_in[5];
  const float* b_head = (const float*)d_in[6];
  const float* W_tail = (const float*)d_in[7];
  const float* b_tail = (const float*)d_in[8];
  const float* W_lin1 = (const float*)d_in[9];
  const float* b_lin1 = (const float*)d_in[10];
  const float* W_lin2 = (const float*)d_in[11];
  const float* b_lin2 = (const float*)d_in[12];
  const float* W_att1 = (const float*)d_in[13];
  const float* b_att1 = (const float*)d_in[14];
  const float* W_att2 = (const float*)d_in[15];
  const float* b_att2 = (const float*)d_in[16];

  float* out_e  = (float*)d_out;
  float* out_eg = out_e + (size_t)NN * DD;

  float* ws = (float*)d_ws;
  const size_t F = (size_t)NN * DD;
  float* e_h   = ws;
  float* e_t   = ws + F;
  float* e_Nh  = ws + 2 * F;
  float* bufA  = ws + 3 * F;     // h1, then bf16 fragment buffers
  float* bufB  = ws + 4 * F;     // h, then candidate keys
  float* rs    = ws + 5 * F;
  float* att   = rs + NN;
  float* stats = att + NN;
  float* topv  = stats + 16;
  int*   topi  = (int*)(topv + (size_t)NN * TOPK);

  unsigned short* ehF = (unsigned short*)bufA;       // F ushorts = 4 MB
  unsigned short* etF = ehF + F;                     // F ushorts = 4 MB
  unsigned* gCand = (unsigned*)bufB;                 // 256*2*32*40 u32 = 2.6 MB

  const dim3 blk(256);
  const dim3 gblk(128);
  const dim3 gemmGrid(NN / 32, DD / 64);             // (256,4) = 1024 blocks

  // h1 = relu(x @ W_fc1 + b1); h = relu(h1 @ W_fc2 + b2)
  gemm_k<1><<<gemmGrid, gblk, 0, stream>>>(x,    W_fc1, b_fc1, bufA, DIN, DD);
  gemm_k<1><<<gemmGrid, gblk, 0, stream>>>(bufA, W_fc2, b_fc2, bufB, DD,  DD);

  // zero rs for gemm2's fused row-sum atomics (h1 dead; bufA reused below)
  hipMemsetAsync(rs, 0, NN * sizeof(float), stream);

  // e_h / e_t + bf16 fragment packs + e_t row sums, all in one fused pass over h.
  // NOTE: gemm2 writes ehF/etF into bufA which aliases h1 (dead) -- but bufB
  // still holds h (the A operand); gCand reuses bufB only after score_cand.
  gemm2_k<<<gemmGrid, gblk, 0, stream>>>(bufB, W_head, b_head, e_h,
                                         W_tail, b_tail, e_t, ehF, etF, rs, DD, DD);

  // candidate generation (h dead after gemm2; bufB reused for gCand)
  score_cand_k<<<dim3(NN / 32, 2), dim3(512), 0, stream>>>(ehF, etF, gCand);
  // merge + fp32 rescore + exact top-30
  cand_merge_k<<<dim3(NN / 32, 2), dim3(512), 0, stream>>>(gCand, e_h, e_t, topv, topi);

  message_k<<<dim3(NN), blk, 0, stream>>>(e_h, e_t, rs, topv, topi, e_Nh);

  // e = relu((e_h+e_Nh)@W_lin1+b1) + relu((e_h*e_Nh)@W_lin2+b2), fused
  gemm_lin_k<<<gemmGrid, gblk, 0, stream>>>(e_h, e_Nh, W_lin1, b_lin1,
                                            W_lin2, b_lin2, out_e, DD, DD);

  // global attention readout
  att_k<<<dim3(NN / 8), blk, 0, stream>>>(out_e, W_att1, b_att1, W_att2, b_att2, att);
  smax_prep_k<<<dim3(1), dim3(1024), 0, stream>>>(att, stats, out_eg);
  eg_k<<<dim3(NN / 32), blk, 0, stream>>>(att, stats, out_e, out_eg);
}

// Round 14
// 625.808 us; speedup vs baseline: 1.0488x; 1.0488x over previous
//
#include <hip/hip_runtime.h>
#include <math.h>

#define NN   8192
#define DIN  1024
#define DD   256
#define TOPK 30
#define KP   40    // candidate list length per slice (bf16 phase)
#define CAP  88    // per-row per-round append buffer (40+88=128 bitonic)
// SAFETY: doubling schedule only! fixed-threshold filtering admits
// E = m*40/n per round; ratio 2 -> E~40 (CAP=88 is +7sigma), ratio 3 -> E~79 (overflows).
// SAFETY: register budget at launch_bounds(512,4) is ~124 VGPR: single MFMA
// accumulator chain + b[8] + LDS threshold reads ONLY. b[16] (r8) or dual
// accumulators / thrv[16] regs (r9) spill -> 200MB scratch traffic, +60us.
// SAFETY: 2 col-slices is the merge/occupancy sweet spot (r10: 4 slices = +71%
// merge-rounds -> +20us). Per-lane atomic appends beat ballot-aggregation
// (r11: ballot+early-out = +16us; conflicts overlap MFMA latency for free).
// SAFETY: do NOT fuse the bf16 fragment pack into gemm2's epilogue (r13):
// the fragment layout makes the stores 8B-scattered (~512B apart per lane)
// -> +30us. pack_frag's coalesced 16B stores are the right shape.
#define NINF -3e38f

typedef short s8v  __attribute__((ext_vector_type(8)));
typedef float f16v __attribute__((ext_vector_type(16)));

// ---------------- wave helpers (wave64) ----------------
__device__ __forceinline__ float wred_sum(float v) {
  v += __shfl_down(v, 32); v += __shfl_down(v, 16); v += __shfl_down(v, 8);
  v += __shfl_down(v, 4);  v += __shfl_down(v, 2);  v += __shfl_down(v, 1);
  return v;  // valid in lane 0
}
__device__ __forceinline__ float wred_max(float v) {
  v = fmaxf(v, __shfl_down(v, 32)); v = fmaxf(v, __shfl_down(v, 16));
  v = fmaxf(v, __shfl_down(v, 8));  v = fmaxf(v, __shfl_down(v, 4));
  v = fmaxf(v, __shfl_down(v, 2));  v = fmaxf(v, __shfl_down(v, 1));
  return v;
}
__device__ __forceinline__ float tanh_fast(float x) {
  return 1.f - 2.f / (__expf(2.f * x) + 1.f);
}
__device__ __forceinline__ unsigned short f2bf(float x) {
  union { float f; unsigned int u; } v; v.f = x;
  unsigned int r = v.u + 0x7FFF + ((v.u >> 16) & 1);
  return (unsigned short)(r >> 16);
}
// strict total order for exact fp32 phase: value desc, index asc
__device__ __forceinline__ bool pair_gt(float v, int i, float pv, int pi) {
  return (v > pv) || (v == pv && i < pi);
}
// monotone float->uint, upper 19 bits of value | 13-bit col (real keys are >0)
__device__ __forceinline__ unsigned key_pack(float f, int col) {
  unsigned b = __float_as_uint(f);
  unsigned u = ((int)b < 0) ? ~b : (b | 0x80000000u);
  return (u & 0xFFFFE000u) | (unsigned)col;
}

// ---------------- generic fp32 GEMM (round-7 proven) ----------------
template<int ACT>
__global__ __launch_bounds__(128, 4)
void gemm_k(const float* __restrict__ A,
            const float* __restrict__ B, const float* __restrict__ bias,
            float* __restrict__ C, int K, int NB)
{
  __shared__ float sA[32 * 36];   // [k][row]
  __shared__ float sB[32 * 68];   // [k][col]
  const int t  = threadIdx.x;
  const int rb = blockIdx.x * 32;
  const int cb = blockIdx.y * 64;
  const int tr = t >> 4;
  const int tc = t & 15;

  float acc[4][4];
#pragma unroll
  for (int u = 0; u < 4; ++u)
#pragma unroll
    for (int j = 0; j < 4; ++j) acc[u][j] = 0.f;

  const int sr  = t >> 2;
  const int sk2 = (t & 3) * 4;

  for (int kt = 0; kt < K; kt += 32) {
    __syncthreads();
    {
      const float* Ap = A + (size_t)(rb + sr) * K + kt;
      float4 va = *(const float4*)(Ap + sk2);
      float4 vb = *(const float4*)(Ap + sk2 + 16);
      sA[(sk2 + 0) * 36 + sr] = va.x; sA[(sk2 + 1) * 36 + sr] = va.y;
      sA[(sk2 + 2) * 36 + sr] = va.z; sA[(sk2 + 3) * 36 + sr] = va.w;
      sA[(sk2 + 16) * 36 + sr] = vb.x; sA[(sk2 + 17) * 36 + sr] = vb.y;
      sA[(sk2 + 18) * 36 + sr] = vb.z; sA[(sk2 + 19) * 36 + sr] = vb.w;
    }
    {
#pragma unroll
      for (int i = 0; i < 4; ++i) {
        const int f4 = t + 128 * i;
        const int k  = f4 >> 4;
        const int c4 = (f4 & 15) << 2;
        *(float4*)&sB[k * 68 + c4] = *(const float4*)&B[(size_t)(kt + k) * NB + cb + c4];
      }
    }
    __syncthreads();
#pragma unroll 8
    for (int k = 0; k < 32; ++k) {
      const float4 bv = *(const float4*)&sB[k * 68 + 4 * tc];
      const float4 av = *(const float4*)&sA[k * 36 + 4 * tr];
      const float a[4] = {av.x, av.y, av.z, av.w};
      const float b[4] = {bv.x, bv.y, bv.z, bv.w};
#pragma unroll
      for (int u = 0; u < 4; ++u)
#pragma unroll
        for (int j = 0; j < 4; ++j) acc[u][j] = fmaf(a[u], b[j], acc[u][j]);
    }
  }

  const float4 bz = *(const float4*)&bias[cb + 4 * tc];
  const float bb[4] = {bz.x, bz.y, bz.z, bz.w};
#pragma unroll
  for (int u = 0; u < 4; ++u) {
    const int row = rb + 4 * tr + u;
    float o[4];
#pragma unroll
    for (int j = 0; j < 4; ++j) {
      o[j] = acc[u][j] + bb[j];
      if (ACT) o[j] = fmaxf(o[j], 0.f);
    }
    float4 ov; ov.x = o[0]; ov.y = o[1]; ov.z = o[2]; ov.w = o[3];
    *(float4*)&C[(size_t)row * NB + cb + 4 * tc] = ov;
  }
}

// ---------------- dual-B GEMM: one A staging, two outputs ----------------
__global__ __launch_bounds__(128, 4)
void gemm2_k(const float* __restrict__ A,
             const float* __restrict__ B1, const float* __restrict__ bias1,
             float* __restrict__ C1,
             const float* __restrict__ B2, const float* __restrict__ bias2,
             float* __restrict__ C2, int K, int NB)
{
  __shared__ float sA[32 * 36];
  __shared__ float sB1[32 * 68];
  __shared__ float sB2[32 * 68];
  const int t  = threadIdx.x;
  const int rb = blockIdx.x * 32;
  const int cb = blockIdx.y * 64;
  const int tr = t >> 4;
  const int tc = t & 15;

  float acc1[4][4], acc2[4][4];
#pragma unroll
  for (int u = 0; u < 4; ++u)
#pragma unroll
    for (int j = 0; j < 4; ++j) { acc1[u][j] = 0.f; acc2[u][j] = 0.f; }

  const int sr  = t >> 2;
  const int sk2 = (t & 3) * 4;

  for (int kt = 0; kt < K; kt += 32) {
    __syncthreads();
    {
      const float* Ap = A + (size_t)(rb + sr) * K + kt;
      float4 va = *(const float4*)(Ap + sk2);
      float4 vb = *(const float4*)(Ap + sk2 + 16);
      sA[(sk2 + 0) * 36 + sr] = va.x; sA[(sk2 + 1) * 36 + sr] = va.y;
      sA[(sk2 + 2) * 36 + sr] = va.z; sA[(sk2 + 3) * 36 + sr] = va.w;
      sA[(sk2 + 16) * 36 + sr] = vb.x; sA[(sk2 + 17) * 36 + sr] = vb.y;
      sA[(sk2 + 18) * 36 + sr] = vb.z; sA[(sk2 + 19) * 36 + sr] = vb.w;
    }
    {
#pragma unroll
      for (int i = 0; i < 4; ++i) {
        const int f4 = t + 128 * i;
        const int k  = f4 >> 4;
        const int c4 = (f4 & 15) << 2;
        *(float4*)&sB1[k * 68 + c4] = *(const float4*)&B1[(size_t)(kt + k) * NB + cb + c4];
        *(float4*)&sB2[k * 68 + c4] = *(const float4*)&B2[(size_t)(kt + k) * NB + cb + c4];
      }
    }
    __syncthreads();
#pragma unroll 4
    for (int k = 0; k < 32; ++k) {
      const float4 b1 = *(const float4*)&sB1[k * 68 + 4 * tc];
      const float4 b2 = *(const float4*)&sB2[k * 68 + 4 * tc];
      const float4 av = *(const float4*)&sA[k * 36 + 4 * tr];
      const float a[4] = {av.x, av.y, av.z, av.w};
      const float v1[4] = {b1.x, b1.y, b1.z, b1.w};
      const float v2[4] = {b2.x, b2.y, b2.z, b2.w};
#pragma unroll
      for (int u = 0; u < 4; ++u)
#pragma unroll
        for (int j = 0; j < 4; ++j) {
          acc1[u][j] = fmaf(a[u], v1[j], acc1[u][j]);
          acc2[u][j] = fmaf(a[u], v2[j], acc2[u][j]);
        }
    }
  }

  const float4 z1 = *(const float4*)&bias1[cb + 4 * tc];
  const float4 z2 = *(const float4*)&bias2[cb + 4 * tc];
  const float c1b[4] = {z1.x, z1.y, z1.z, z1.w};
  const float c2b[4] = {z2.x, z2.y, z2.z, z2.w};
#pragma unroll
  for (int u = 0; u < 4; ++u) {
    const int row = rb + 4 * tr + u;
    float4 o1, o2;
    o1.x = acc1[u][0] + c1b[0]; o1.y = acc1[u][1] + c1b[1];
    o1.z = acc1[u][2] + c1b[2]; o1.w = acc1[u][3] + c1b[3];
    o2.x = acc2[u][0] + c2b[0]; o2.y = acc2[u][1] + c2b[1];
    o2.z = acc2[u][2] + c2b[2]; o2.w = acc2[u][3] + c2b[3];
    *(float4*)&C1[(size_t)row * NB + cb + 4 * tc] = o1;
    *(float4*)&C2[(size_t)row * NB + cb + 4 * tc] = o2;
  }
}

// ---------------- fused lin1/lin2 GEMM ----------------
__global__ __launch_bounds__(128, 4)
void gemm_lin_k(const float* __restrict__ Eh, const float* __restrict__ En,
                const float* __restrict__ B1, const float* __restrict__ bias1,
                const float* __restrict__ B2, const float* __restrict__ bias2,
                float* __restrict__ C, int K, int NB)
{
  __shared__ float sA1[32 * 36];   // eh+eN
  __shared__ float sA2[32 * 36];   // eh*eN
  __shared__ float sB1[32 * 68];
  __shared__ float sB2[32 * 68];
  const int t  = threadIdx.x;
  const int rb = blockIdx.x * 32;
  const int cb = blockIdx.y * 64;
  const int tr = t >> 4;
  const int tc = t & 15;

  float acc1[4][4], acc2[4][4];
#pragma unroll
  for (int u = 0; u < 4; ++u)
#pragma unroll
    for (int j = 0; j < 4; ++j) { acc1[u][j] = 0.f; acc2[u][j] = 0.f; }

  const int sr  = t >> 2;
  const int sk2 = (t & 3) * 4;

  for (int kt = 0; kt < K; kt += 32) {
    __syncthreads();
    {
      const float* Hp = Eh + (size_t)(rb + sr) * K + kt;
      const float* Np = En + (size_t)(rb + sr) * K + kt;
      const float4 ha = *(const float4*)(Hp + sk2);
      const float4 hb = *(const float4*)(Hp + sk2 + 16);
      const float4 na = *(const float4*)(Np + sk2);
      const float4 nb = *(const float4*)(Np + sk2 + 16);
      sA1[(sk2 + 0) * 36 + sr] = ha.x + na.x; sA2[(sk2 + 0) * 36 + sr] = ha.x * na.x;
      sA1[(sk2 + 1) * 36 + sr] = ha.y + na.y; sA2[(sk2 + 1) * 36 + sr] = ha.y * na.y;
      sA1[(sk2 + 2) * 36 + sr] = ha.z + na.z; sA2[(sk2 + 2) * 36 + sr] = ha.z * na.z;
      sA1[(sk2 + 3) * 36 + sr] = ha.w + na.w; sA2[(sk2 + 3) * 36 + sr] = ha.w * na.w;
      sA1[(sk2 + 16) * 36 + sr] = hb.x + nb.x; sA2[(sk2 + 16) * 36 + sr] = hb.x * nb.x;
      sA1[(sk2 + 17) * 36 + sr] = hb.y + nb.y; sA2[(sk2 + 17) * 36 + sr] = hb.y * nb.y;
      sA1[(sk2 + 18) * 36 + sr] = hb.z + nb.z; sA2[(sk2 + 18) * 36 + sr] = hb.z * nb.z;
      sA1[(sk2 + 19) * 36 + sr] = hb.w + nb.w; sA2[(sk2 + 19) * 36 + sr] = hb.w * nb.w;
    }
    {
#pragma unroll
      for (int i = 0; i < 4; ++i) {
        const int f4 = t + 128 * i;
        const int k  = f4 >> 4;
        const int c4 = (f4 & 15) << 2;
        *(float4*)&sB1[k * 68 + c4] = *(const float4*)&B1[(size_t)(kt + k) * NB + cb + c4];
        *(float4*)&sB2[k * 68 + c4] = *(const float4*)&B2[(size_t)(kt + k) * NB + cb + c4];
      }
    }
    __syncthreads();
#pragma unroll 4
    for (int k = 0; k < 32; ++k) {
      const float4 b1 = *(const float4*)&sB1[k * 68 + 4 * tc];
      const float4 b2 = *(const float4*)&sB2[k * 68 + 4 * tc];
      const float4 a1 = *(const float4*)&sA1[k * 36 + 4 * tr];
      const float4 a2 = *(const float4*)&sA2[k * 36 + 4 * tr];
      const float x1[4] = {a1.x, a1.y, a1.z, a1.w};
      const float x2[4] = {a2.x, a2.y, a2.z, a2.w};
      const float v1[4] = {b1.x, b1.y, b1.z, b1.w};
      const float v2[4] = {b2.x, b2.y, b2.z, b2.w};
#pragma unroll
      for (int u = 0; u < 4; ++u)
#pragma unroll
        for (int j = 0; j < 4; ++j) {
          acc1[u][j] = fmaf(x1[u], v1[j], acc1[u][j]);
          acc2[u][j] = fmaf(x2[u], v2[j], acc2[u][j]);
        }
    }
  }

  const float4 z1 = *(const float4*)&bias1[cb + 4 * tc];
  const float4 z2 = *(const float4*)&bias2[cb + 4 * tc];
  const float c1b[4] = {z1.x, z1.y, z1.z, z1.w};
  const float c2b[4] = {z2.x, z2.y, z2.z, z2.w};
#pragma unroll
  for (int u = 0; u < 4; ++u) {
    const int row = rb + 4 * tr + u;
    float4 ov;
    ov.x = fmaxf(acc1[u][0] + c1b[0], 0.f) + fmaxf(acc2[u][0] + c2b[0], 0.f);
    ov.y = fmaxf(acc1[u][1] + c1b[1], 0.f) + fmaxf(acc2[u][1] + c2b[1], 0.f);
    ov.z = fmaxf(acc1[u][2] + c1b[2], 0.f) + fmaxf(acc2[u][2] + c2b[2], 0.f);
    ov.w = fmaxf(acc1[u][3] + c1b[3], 0.f) + fmaxf(acc2[u][3] + c2b[3], 0.f);
    *(float4*)&C[(size_t)row * NB + cb + 4 * tc] = ov;
  }
}

// ---------------- pack fp32 [N][256] into bf16 MFMA-fragment order ----------------
// grid.y selects (e_h -> ehF) / (e_t -> etF). The e_t pass also accumulates
// row sums into rs (pre-zeroed): each thread holds 8 contiguous fp32 of one row.
__global__ __launch_bounds__(256)
void pack_frag_k(const float* __restrict__ srcA, unsigned short* __restrict__ dstA,
                 const float* __restrict__ srcB, unsigned short* __restrict__ dstB,
                 float* __restrict__ rs)
{
  const int isB = blockIdx.y;
  const float* src = isB ? srcB : srcA;
  unsigned short* dst = isB ? dstB : dstA;
  const int c = blockIdx.x * 256 + threadIdx.x;     // 0 .. 262143
  const int l = c & 63;
  const int W = (c >> 6) & 15;
  const int T = c >> 10;
  const int col = T * 32 + (l & 31);
  const int k0  = W * 16 + ((l >> 5) << 3);
  const float4 a = *(const float4*)&src[(size_t)col * DD + k0];
  const float4 b = *(const float4*)&src[(size_t)col * DD + k0 + 4];
  uint4 o;
  o.x = (unsigned)f2bf(a.x) | ((unsigned)f2bf(a.y) << 16);
  o.y = (unsigned)f2bf(a.z) | ((unsigned)f2bf(a.w) << 16);
  o.z = (unsigned)f2bf(b.x) | ((unsigned)f2bf(b.y) << 16);
  o.w = (unsigned)f2bf(b.z) | ((unsigned)f2bf(b.w) << 16);
  *(uint4*)&dst[(size_t)c * 8] = o;
  if (isB) {
    const float s = ((a.x + a.y) + (a.z + a.w)) + ((b.x + b.y) + (b.z + b.w));
    atomicAdd(&rs[col], s);
  }
}

// ---------------- candidate generation: bf16 MFMA + key-packed top-40 ----------------
// grid (256 row-groups, 2 col-slices) = 512 blocks, 512 threads (8 waves).
// 7 DOUBLING rounds; r7-proven register shape; per-lane atomic appends;
// per-row bitonic-128 merges, 2 rows interleaved per wave.
__global__ __launch_bounds__(512, 4)
void score_cand_k(const unsigned short* __restrict__ ehF,
                  const unsigned short* __restrict__ etF,
                  unsigned* __restrict__ gCand)
{
  __shared__ unsigned sBuf[32 * CAP];
  __shared__ unsigned sK[32][KP];
  __shared__ unsigned sThrK[32];
  __shared__ int      sCnt[32];

  const int t = threadIdx.x, lane = t & 63, w = t >> 6;
  const int g  = blockIdx.x;            // row group
  const int sy = blockIdx.y;            // col slice (0..1)
  const int tile0 = sy * 128;
  const s8v* eh8 = (const s8v*)ehF;
  const s8v* et8 = (const s8v*)etF;

  s8v af[16];
#pragma unroll
  for (int W = 0; W < 16; ++W)
    af[W] = eh8[((size_t)g * 16 + W) * 64 + lane];

  for (int idx = t; idx < 32 * KP; idx += 512) ((unsigned*)sK)[idx] = 0u;
  if (t < 32) { sThrK[t] = 0u; sCnt[t] = 0; }
  __syncthreads();

  const int rq = 4 * (lane >> 5);
  const int colLane = lane & 31;

  int tb = 0;
  for (int rnd = 0; rnd < 7; ++rnd) {
    const int ntile = (rnd == 0) ? 2 : (2 << (rnd - 1));   // 2,2,4,8,16,32,64
    for (int p = w; p < ntile; p += 8) {
      const int T = tile0 + tb + p;
      const s8v* bp = et8 + (size_t)T * 1024 + lane;
      f16v c;
#pragma unroll
      for (int i = 0; i < 16; ++i) c[i] = 0.f;
      {
        s8v b[8];
#pragma unroll
        for (int q = 0; q < 8; ++q) b[q] = bp[q * 64];
#pragma unroll
        for (int q = 0; q < 8; ++q)
          c = __builtin_amdgcn_mfma_f32_32x32x16_bf16(af[q], b[q], c, 0, 0, 0);
#pragma unroll
        for (int q = 0; q < 8; ++q) b[q] = bp[(8 + q) * 64];
#pragma unroll
        for (int q = 0; q < 8; ++q)
          c = __builtin_amdgcn_mfma_f32_32x32x16_bf16(af[8 + q], b[q], c, 0, 0, 0);
      }
      const int col = T * 32 + colLane;
#pragma unroll
      for (int r = 0; r < 16; ++r) {
        const int row = (r & 3) + 8 * (r >> 2) + rq;
        const unsigned key = key_pack(c[r], col);
        if (key > sThrK[row]) {
          const int ix = atomicAdd(&sCnt[row], 1);
          if (ix < CAP) sBuf[row * CAP + ix] = key;
        }
      }
    }
    __syncthreads();

#pragma unroll 1
    for (int rp = 0; rp < 2; ++rp) {
      const int ra = 4 * w + 2 * rp;
      const int rc = ra + 1;
      const int cA = min(sCnt[ra], CAP);
      const int cB = min(sCnt[rc], CAP);
      unsigned a0 = (lane < KP) ? sK[ra][lane]
                                : ((lane - KP) < cA ? sBuf[ra * CAP + (lane - KP)] : 0u);
      unsigned a1 = ((24 + lane) < cA) ? sBuf[ra * CAP + 24 + lane] : 0u;
      unsigned b0 = (lane < KP) ? sK[rc][lane]
                                : ((lane - KP) < cB ? sBuf[rc * CAP + (lane - KP)] : 0u);
      unsigned b1 = ((24 + lane) < cB) ? sBuf[rc * CAP + 24 + lane] : 0u;
#pragma unroll
      for (int k = 2; k <= 128; k <<= 1) {
#pragma unroll
        for (int j = k >> 1; j >= 1; j >>= 1) {
          if (j == 64) {
            unsigned mx = max(a0, a1), mn = min(a0, a1); a0 = mx; a1 = mn;
            mx = max(b0, b1); mn = min(b0, b1); b0 = mx; b1 = mn;
          } else {
            const unsigned pa0 = (unsigned)__shfl_xor((int)a0, j);
            const unsigned pa1 = (unsigned)__shfl_xor((int)a1, j);
            const unsigned pb0 = (unsigned)__shfl_xor((int)b0, j);
            const unsigned pb1 = (unsigned)__shfl_xor((int)b1, j);
            const bool km0 = (((lane & k) == 0)        == ((lane & j) == 0));
            const bool km1 = ((((64 + lane) & k) == 0) == ((lane & j) == 0));
            a0 = km0 ? max(a0, pa0) : min(a0, pa0);
            a1 = km1 ? max(a1, pa1) : min(a1, pa1);
            b0 = km0 ? max(b0, pb0) : min(b0, pb0);
            b1 = km1 ? max(b1, pb1) : min(b1, pb1);
          }
        }
      }
      if (rnd < 6) {
        if (lane < KP) { sK[ra][lane] = a0; sK[rc][lane] = b0; }
        if (lane == KP - 1) { sThrK[ra] = a0; sThrK[rc] = b0; }
        if (lane == 0) { sCnt[ra] = 0; sCnt[rc] = 0; }
      } else {
        if (lane < KP) {
          gCand[(((size_t)g * 2 + sy) * 32 + ra) * KP + lane] = a0;
          gCand[(((size_t)g * 2 + sy) * 32 + rc) * KP + lane] = b0;
        }
      }
    }
    __syncthreads();
    tb += ntile;
  }
}

// ---------------- merge slices + fp32 rescore + exact top-30 ----------------
__global__ __launch_bounds__(512, 2)
void cand_merge_k(const unsigned* __restrict__ gCand,
                  const float* __restrict__ e_h, const float* __restrict__ e_t,
                  float* __restrict__ topv_g, int* __restrict__ topi_g)
{
  __shared__ float    sEh[16 * 256];
  __shared__ unsigned sK40[16][KP];
  __shared__ float    sRes[16][KP];
  const int t = threadIdx.x, lane = t & 63, w = t >> 6;
  const int g = blockIdx.x, rb = g * 32;
  const int r0 = blockIdx.y * 16;

  for (int i = t; i < 1024; i += 512)
    ((float4*)sEh)[i] = ((const float4*)(e_h + (size_t)(rb + r0) * 256))[i];

#pragma unroll 1
  for (int rp = 0; rp < 2; ++rp) {
    const int lr = 2 * w + rp;
    const int r  = r0 + lr;
    unsigned v0, v1;
    {
      const int m = lane;
      const int s = m / 40, q = m - s * 40;
      v0 = gCand[(((size_t)g * 2 + s) * 32 + r) * KP + q];
    }
    {
      const int m = 64 + lane;
      if (m < 80) {
        const int q = m - 40;
        v1 = gCand[(((size_t)g * 2 + 1) * 32 + r) * KP + q];
      } else v1 = 0u;
    }
#pragma unroll
    for (int k = 2; k <= 128; k <<= 1) {
#pragma unroll
      for (int j = k >> 1; j >= 1; j >>= 1) {
        if (j == 64) {
          const unsigned mx = max(v0, v1), mn = min(v0, v1);
          v0 = mx; v1 = mn;
        } else {
          const unsigned p0 = (unsigned)__shfl_xor((int)v0, j);
          const unsigned p1 = (unsigned)__shfl_xor((int)v1, j);
          const bool km0 = (((lane & k) == 0)        == ((lane & j) == 0));
          const bool km1 = ((((64 + lane) & k) == 0) == ((lane & j) == 0));
          v0 = km0 ? max(v0, p0) : min(v0, p0);
          v1 = km1 ? max(v1, p1) : min(v1, p1);
        }
      }
    }
    if (lane < KP) sK40[lr][lane] = v0;
  }
  __syncthreads();

  for (int i = t; i < 16 * KP; i += 512) {
    const int lr = i / KP, q = i - lr * KP;
    const int c = (int)(sK40[lr][q] & 0x1FFFu);
    const float* et = &e_t[(size_t)c * 256];
    const float* eh = &sEh[lr * 256];
    float acc = 0.f;
#pragma unroll 8
    for (int d = 0; d < 64; ++d) {
      const float4 a = *(const float4*)&eh[d * 4];
      const float4 b = *(const float4*)&et[d * 4];
      acc = fmaf(a.x, b.x, acc); acc = fmaf(a.y, b.y, acc);
      acc = fmaf(a.z, b.z, acc); acc = fmaf(a.w, b.w, acc);
    }
    sRes[lr][q] = acc * 0.0625f;                 // SCALE = D^-0.5
  }
  __syncthreads();

#pragma unroll 1
  for (int rp = 0; rp < 2; ++rp) {
    const int lr = 2 * w + rp;
    float v; int c;
    if (lane < KP) { v = sRes[lr][lane]; c = (int)(sK40[lr][lane] & 0x1FFFu); }
    else           { v = NINF;           c = 0x40000000 + lane; }
#pragma unroll
    for (int k = 2; k <= 64; k <<= 1) {
#pragma unroll
      for (int j = k >> 1; j >= 1; j >>= 1) {
        const float pv = __shfl_xor(v, j);
        const int   pc = __shfl_xor(c, j);
        const bool km = (((lane & k) == 0) == ((lane & j) == 0));
        const bool gt = pair_gt(v, c, pv, pc);
        const bool keep = (km == gt);
        v = keep ? v : pv; c = keep ? c : pc;
      }
    }
    if (lane < TOPK) {
      topv_g[(size_t)(rb + r0 + lr) * TOPK + lane] = v;
      topi_g[(size_t)(rb + r0 + lr) * TOPK + lane] = c;
    }
  }
}

// ---------------- gated message construction -> e_Nh ----------------
// Batched reduction: 30 tanh values, then 6 shuffle stages with 30-way ILP.
__global__ __launch_bounds__(256)
void message_k(const float* __restrict__ e_h, const float* __restrict__ e_t,
               const float* __restrict__ rs, const float* __restrict__ tv_g,
               const int* __restrict__ ti_g, float* __restrict__ e_Nh)
{
  __shared__ float sP[TOPK];
  __shared__ int   sI[TOPK];
  __shared__ float sW[TOPK];
  __shared__ float wpart[TOPK][4];
  const int n = blockIdx.x;
  const int t = threadIdx.x, lane = t & 63, w = t >> 6;

  if (w == 0) {
    const float v = (lane < TOPK) ? tv_g[(size_t)n * TOPK + lane] : NINF;
    float m = wred_max(v); m = __shfl(m, 0);
    const float p = (lane < TOPK) ? __expf(v - m) : 0.f;
    float s = wred_sum(p); s = __shfl(s, 0);
    if (lane < TOPK) { sP[lane] = p / s; sI[lane] = ti_g[(size_t)n * TOPK + lane]; }
  }
  __syncthreads();

  const float eh = e_h[(size_t)n * DD + t];
  float nbv[TOPK];
  float gg[TOPK];
#pragma unroll
  for (int k = 0; k < TOPK; ++k) {
    const int   j = sI[k];
    const float p = sP[k];
    const float nb = e_t[(size_t)j * DD + t];
    nbv[k] = nb;
    gg[k] = tanh_fast((2.f - p) * eh + p * nb);
  }
#pragma unroll
  for (int off = 32; off >= 1; off >>= 1)
#pragma unroll
    for (int k = 0; k < TOPK; ++k)
      gg[k] += __shfl_down(gg[k], off);
  if (lane == 0)
#pragma unroll
    for (int k = 0; k < TOPK; ++k) wpart[k][w] = gg[k];
  __syncthreads();

  if (w == 0) {
    float kw = NINF;
    if (lane < TOPK) {
      const float gs = wpart[lane][0] + wpart[lane][1] + wpart[lane][2] + wpart[lane][3];
      kw = rs[sI[lane]] * gs;
    }
    float m = wred_max(kw); m = __shfl(m, 0);
    const float p = (lane < TOPK) ? __expf(kw - m) : 0.f;
    float s = wred_sum(p); s = __shfl(s, 0);
    if (lane < TOPK) sW[lane] = p / s;
  }
  __syncthreads();

  float o = 0.f;
#pragma unroll
  for (int k = 0; k < TOPK; ++k) o = fmaf(sW[k], nbv[k], o);
  e_Nh[(size_t)n * DD + t] = o;
}

// ---------------- attention readout: att[n] ----------------
__global__ __launch_bounds__(256)
void att_k(const float* __restrict__ e, const float* __restrict__ W1,
           const float* __restrict__ b1, const float* __restrict__ W2,
           const float* __restrict__ b2, float* __restrict__ att)
{
  const int t = threadIdx.x;
  const int q = t >> 7;
  const int m = t & 127;
  const int lane = t & 63, w = t >> 6;
  const int n0 = blockIdx.x * 8 + q * 4;
  float acc[4] = {0.f, 0.f, 0.f, 0.f};
  for (int d = 0; d < DD; ++d) {
    const float wv = W1[d * 128 + m];
#pragma unroll
    for (int rr = 0; rr < 4; ++rr)
      acc[rr] = fmaf(e[(size_t)(n0 + rr) * DD + d], wv, acc[rr]);
  }
  const float b1m = b1[m], w2m = W2[m];
  __shared__ float part[4][4];
#pragma unroll
  for (int rr = 0; rr < 4; ++rr) {
    float v = acc[rr] + b1m;
    v = (v > 0.f) ? v : 0.01f * v;
    v *= w2m;
    v = wred_sum(v);
    if (lane == 0) part[w][rr] = v;
  }
  __syncthreads();
  if (t < 8) {
    const int qq = t >> 2, rr = t & 3;
    att[blockIdx.x * 8 + qq * 4 + rr] = part[qq * 2][rr] + part[qq * 2 + 1][rr] + b2[0];
  }
}

// ---------------- softmax stats over N, zero e_g ----------------
__global__ __launch_bounds__(1024)
void smax_prep_k(const float* __restrict__ att, float* __restrict__ stats,
                 float* __restrict__ eg)
{
  __shared__ float red[16];
  __shared__ float mg;
  const int t = threadIdx.x, lane = t & 63, w = t >> 6;
  float m = NINF;
#pragma unroll
  for (int i = 0; i < 8; ++i) m = fmaxf(m, att[t + 1024 * i]);
  m = wred_max(m);
  if (lane == 0) red[w] = m;
  __syncthreads();
  if (t == 0) {
    float mm = red[0];
    for (int i = 1; i < 16; ++i) mm = fmaxf(mm, red[i]);
    mg = mm;
  }
  __syncthreads();
  const float mm = mg;
  float s = 0.f;
#pragma unroll
  for (int i = 0; i < 8; ++i) s += __expf(att[t + 1024 * i] - mm);
  s = wred_sum(s);
  __syncthreads();
  if (lane == 0) red[w] = s;
  __syncthreads();
  if (t == 0) {
    float ss = 0.f;
    for (int i = 0; i < 16; ++i) ss += red[i];
    stats[0] = mm; stats[1] = ss;
  }
  if (t < DD) eg[t] = 0.f;
}

// ---------------- e_g = sum_n softmax(att)_n * e_n ----------------
__global__ __launch_bounds__(256)
void eg_k(const float* __restrict__ att, const float* __restrict__ stats,
          const float* __restrict__ e, float* __restrict__ eg)
{
  const int t = threadIdx.x;
  const float m = stats[0], inv = 1.f / stats[1];
  float acc = 0.f;
  const int n0 = blockIdx.x * 128;
  for (int r = 0; r < 128; ++r) {
    const int n = n0 + r;
    acc = fmaf(__expf(att[n] - m), e[(size_t)n * DD + t], acc);
  }
  atomicAdd(&eg[t], acc * inv);
}

// ---------------- launch ----------------
extern "C" void kernel_launch(void* const* d_in, const int* in_sizes, int n_in,
                              void* d_out, int out_size, void* d_ws, size_t ws_size,
                              hipStream_t stream)
{
  const float* x      = (const float*)d_in[0];
  const float* W_fc1  = (const float*)d_in[1];
  const float* b_fc1  = (const float*)d_in[2];
  const float* W_fc2  = (const float*)d_in[3];
  const float* b_fc2  = (const float*)d_in[4];
  const float* W_head = (const float*)d_in[5];
  const float* b_head = (const float*)d_in[6];
  const float* W_tail = (const float*)d_in[7];
  const float* b_tail = (const float*)d_in[8];
  const float* W_lin1 = (const float*)d_in[9];
  const float* b_lin1 = (const float*)d_in[10];
  const float* W_lin2 = (const float*)d_in[11];
  const float* b_lin2 = (const float*)d_in[12];
  const float* W_att1 = (const float*)d_in[13];
  const float* b_att1 = (const float*)d_in[14];
  const float* W_att2 = (const float*)d_in[15];
  const float* b_att2 = (const float*)d_in[16];

  float* out_e  = (float*)d_out;
  float* out_eg = out_e + (size_t)NN * DD;

  float* ws = (float*)d_ws;
  const size_t F = (size_t)NN * DD;
  float* e_h   = ws;
  float* e_t   = ws + F;
  float* e_Nh  = ws + 2 * F;
  float* bufA  = ws + 3 * F;     // h1, then bf16 fragment buffers
  float* bufB  = ws + 4 * F;     // h, then candidate keys
  float* rs    = ws + 5 * F;
  float* att   = rs + NN;
  float* stats = att + NN;
  float* topv  = stats + 16;
  int*   topi  = (int*)(topv + (size_t)NN * TOPK);

  unsigned short* ehF = (unsigned short*)bufA;       // F ushorts = 4 MB
  unsigned short* etF = ehF + F;                     // F ushorts = 4 MB
  unsigned* gCand = (unsigned*)bufB;                 // 256*2*32*40 u32 = 2.6 MB

  const dim3 blk(256);
  const dim3 gblk(128);
  const dim3 gemmGrid(NN / 32, DD / 64);             // (256,4) = 1024 blocks

  // h1 = relu(x @ W_fc1 + b1); h = relu(h1 @ W_fc2 + b2)
  gemm_k<1><<<gemmGrid, gblk, 0, stream>>>(x,    W_fc1, b_fc1, bufA, DIN, DD);
  gemm_k<1><<<gemmGrid, gblk, 0, stream>>>(bufA, W_fc2, b_fc2, bufB, DD,  DD);
  // e_h / e_t in one fused pass over h
  gemm2_k<<<gemmGrid, gblk, 0, stream>>>(bufB, W_head, b_head, e_h,
                                         W_tail, b_tail, e_t, DD, DD);

  // zero rs for pack_frag's fused row-sum atomics
  hipMemsetAsync(rs, 0, NN * sizeof(float), stream);
  // bf16 fragment-order packs (h1 dead; bufA reused) + e_t row sums fused
  pack_frag_k<<<dim3(NN * DD / 8 / 256, 2), blk, 0, stream>>>(e_h, ehF, e_t, etF, rs);

  // candidate generation (h dead; bufB reused for gCand)
  score_cand_k<<<dim3(NN / 32, 2), dim3(512), 0, stream>>>(ehF, etF, gCand);
  // merge + fp32 rescore + exact top-30
  cand_merge_k<<<dim3(NN / 32, 2), dim3(512), 0, stream>>>(gCand, e_h, e_t, topv, topi);

  message_k<<<dim3(NN), blk, 0, stream>>>(e_h, e_t, rs, topv, topi, e_Nh);

  // e = relu((e_h+e_Nh)@W_lin1+b1) + relu((e_h*e_Nh)@W_lin2+b2), fused
  gemm_lin_k<<<gemmGrid, gblk, 0, stream>>>(e_h, e_Nh, W_lin1, b_lin1,
                                            W_lin2, b_lin2, out_e, DD, DD);

  // global attention readout
  att_k<<<dim3(NN / 8), blk, 0, stream>>>(out_e, W_att1, b_att1, W_att2, b_att2, att);
  smax_prep_k<<<dim3(1), dim3(1024), 0, stream>>>(att, stats, out_eg);
  eg_k<<<dim3(64), blk, 0, stream>>>(att, stats, out_e, out_eg);
}